// Round 16
// baseline (289.338 us; speedup 1.0000x reference)
//
#include <hip/hip_runtime.h>
#include <cstddef>

#define NN 32
#define CC 96
#define TT 1024
#define PP 10240          // T*V, contiguous per (n,c)
#define NEG 0.1f
#define GCH 8             // k_gram: t-chunks per block (8 x 80p)
#define MCH 8             // k_mix:  80p-chunks per block (512 blocks = 2/CU, 1 cohort)

typedef __attribute__((ext_vector_type(8))) short s16x8;
typedef __attribute__((ext_vector_type(4))) float f32x4;
typedef unsigned short ushort_t;
typedef unsigned int uint_t;
typedef unsigned long long ull_t;

// ---- workspace layout (float offsets) ----
#define OFF_ATT  ((size_t)NN*128*300)              // attsum: f32 [N][300] (atomic accum)
#define OFF_WBF  (OFF_ATT + (size_t)NN*300)        // wbf: bf16 [288][96]
#define OFF_WFB  (OFF_WBF + (size_t)13824)         // wfb: bf16 [96][96] BN-folded
#define OFF_BF   (OFF_WFB + (size_t)4608)          // bfold: f32 [96]

#define VP 82      // vls pitch (ushorts) for 80-p tiles
#define YP 102     // y0T pitch: 51 words/row, gcd(51%32=19,32)=1 -> conflict-free writes

__device__ __forceinline__ ushort_t f2bf(float f) {
    union { float f; uint_t u; } a; a.f = f;
    const uint_t r = a.u + 0x7FFFu + ((a.u >> 16) & 1u);   // RNE
    return (ushort_t)(r >> 16);
}
__device__ __forceinline__ float bf2f(ushort_t h) {
    union { uint_t u; float f; } a; a.u = ((uint_t)h) << 16;
    return a.f;
}
// inline tanh: no OCML call, no branches. |err| ~1e-7.
__device__ __forceinline__ float tanh_inl(float z) {
    z = fminf(fmaxf(z, -10.f), 10.f);
    const float e2 = __expf(2.f * z);
    return (e2 - 1.f) / (e2 + 1.f);
}

// ---------- prep: bf16 weights + BN fold + attsum zero ----------
__global__ void k_prep(const float* __restrict__ wqkv, const float* __restrict__ wff,
                       const float* __restrict__ bff,  const float* __restrict__ gam,
                       const float* __restrict__ bet,  const float* __restrict__ mu,
                       const float* __restrict__ var,  float* __restrict__ ws) {
    const int i = blockIdx.x * 256 + threadIdx.x;
    const int stride = gridDim.x * 256;
    ushort_t* wbf = (ushort_t*)(ws + OFF_WBF);
    for (int j = i; j < 288 * 96; j += stride) wbf[j] = f2bf(wqkv[j]);   // row-major [o][c]
    ushort_t* wfb = (ushort_t*)(ws + OFF_WFB);
    for (int j = i; j < 96 * 96; j += stride) {
        const int o = j / 96;                    // row-major [o][sc]
        const float A = gam[o] * rsqrtf(var[o] + 1e-5f);
        wfb[j] = f2bf(wff[j] * A);
    }
    for (int j = i; j < 96; j += stride) {
        const float A = gam[j] * rsqrtf(var[j] + 1e-5f);
        ws[OFF_BF + j] = (bff[j] - mu[j]) * A + bet[j];
    }
    for (int j = i; j < NN * 300; j += stride) ws[OFF_ATT + j] = 0.f;   // atomic accum
}

// ---------- gram: pipelined chunk loop; q,k proj + gram partials -> 1 atomic ----------
// UNCHANGED (HW-verified ~34 us).
__global__ __launch_bounds__(640) void k_gram(const float* __restrict__ x,
                                              const ushort_t* __restrict__ wbf,
                                              const float* __restrict__ bqkv,
                                              float* __restrict__ attsum) {
    __shared__ ushort_t xT[80][104];        // 16,640 B  xT[p][c]
    __shared__ ushort_t qk[6][8][10][36];   // 34,560 B  [role*3+s][t][u][cp(pad36)]
    __shared__ float red[6][100];           //  2,400 B  -> 53,600 total
    const int n = blockIdx.y, tcb = blockIdx.x;    // tcb in [0,16)
    const int tid = threadIdx.x;
    const int l = tid & 63, w = tid >> 6;          // w in [0,10)
    const int lr = l & 15, lh = l >> 4;
    const int ct = w >> 1, rth = w & 1;
    const int p2p = ct * 16 + lr;                  // P2 column owned by this lane

    int c4a[3], ppa[3];
#pragma unroll
    for (int it = 0; it < 3; it++) {
        const int i = tid + it * 640;              // i < 1920
        c4a[it] = i / 80; ppa[it] = i % 80;
    }

    const float* xn = x + (size_t)n * CC * PP;
    float xr[12];
    {
        const float* xsrc = xn + (size_t)(tcb * GCH) * 80;
#pragma unroll
        for (int it = 0; it < 3; it++)
#pragma unroll
            for (int r = 0; r < 4; r++)
                xr[it * 4 + r] = xsrc[(size_t)(4 * c4a[it] + r) * PP + ppa[it]];
    }

    float gacc = 0.f;
    for (int j = 0; j < GCH; j++) {
        // ---- pack xr -> xT (bf16, 4-c packed b64 writes) ----
#pragma unroll
        for (int it = 0; it < 3; it++) {
            const uint_t lo = (uint_t)f2bf(xr[it * 4 + 0]) | ((uint_t)f2bf(xr[it * 4 + 1]) << 16);
            const uint_t hi = (uint_t)f2bf(xr[it * 4 + 2]) | ((uint_t)f2bf(xr[it * 4 + 3]) << 16);
            *(ull_t*)&xT[ppa[it]][4 * c4a[it]] = (ull_t)lo | ((ull_t)hi << 32);
        }
        __syncthreads();

        // ---- prefetch next chunk into regs; drains under P2+P3 compute ----
        if (j + 1 < GCH) {
            const float* xsrc = xn + (size_t)(tcb * GCH + j + 1) * 80;
#pragma unroll
            for (int it = 0; it < 3; it++)
#pragma unroll
                for (int r = 0; r < 4; r++)
                    xr[it * 4 + r] = xsrc[(size_t)(4 * c4a[it] + r) * PP + ppa[it]];
        }

        // ---- P2: q,k projection; 10 wave-tasks = 5 ct x 2 roles, 6 rt each ----
        {
            s16x8 bfr[3];
#pragma unroll
            for (int kb = 0; kb < 3; kb++)
                bfr[kb] = *(const s16x8*)&xT[p2p][kb * 32 + lh * 8];
            ushort_t* qkf = (ushort_t*)qk;
#pragma unroll
            for (int jj = 0; jj < 6; jj++) {
                const int rt = rth * 6 + jj;
                f32x4 acc = {0.f, 0.f, 0.f, 0.f};
#pragma unroll
                for (int kb = 0; kb < 3; kb++) {
                    const s16x8 afr = *(const s16x8*)&wbf[(size_t)(rt * 16 + lr) * 96 + kb * 32 + lh * 8];
                    acc = __builtin_amdgcn_mfma_f32_16x16x32_bf16(afr, bfr[kb], acc, 0, 0, 0);
                }
                const int obase = rt * 16 + lh * 4;
                const float4 bb = *(const float4*)&bqkv[obase];
                const int role = rth;                 // rt<6 -> q, rt>=6 -> k
                const int orem = obase - role * 96;
                const int s = orem >> 5, cp0 = orem & 31;
                const uint_t lo = (uint_t)f2bf(acc[0] + bb.x) | ((uint_t)f2bf(acc[1] + bb.y) << 16);
                const uint_t hi = (uint_t)f2bf(acc[2] + bb.z) | ((uint_t)f2bf(acc[3] + bb.w) << 16);
                *(ull_t*)(qkf + ((size_t)(role * 3 + s) * 80 + p2p) * 36 + cp0) =
                    (ull_t)lo | ((ull_t)hi << 32);    // 8B-aligned (72B rows)
            }
        }
        __syncthreads();

        // ---- P3: gram G_s[u][v] = sum_{cp,t} q[s,cp,t,u] k[s,cp,t,v] ----
        if (w < 6) {
            const int s = w >> 1, th = w & 1;
            const int uv = lr > 9 ? 9 : lr;     // clamp garbage rows/cols (discarded)
            f32x4 g = {0.f, 0.f, 0.f, 0.f};
#pragma unroll
            for (int t4 = 0; t4 < 4; t4++) {
                const int t = th * 4 + t4;
                const ushort_t* qp = &qk[s][t][uv][lh * 8];       // 8B-aligned
                const ushort_t* kp = &qk[3 + s][t][uv][lh * 8];
                union { ull_t u[2]; s16x8 v; } ua, ub;
                ua.u[0] = *(const ull_t*)qp;  ua.u[1] = *(const ull_t*)(qp + 4);
                ub.u[0] = *(const ull_t*)kp;  ub.u[1] = *(const ull_t*)(kp + 4);
                g = __builtin_amdgcn_mfma_f32_16x16x32_bf16(ua.v, ub.v, g, 0, 0, 0);
            }
#pragma unroll
            for (int r = 0; r < 4; r++) {
                const int u = lh * 4 + r;
                if (u < 10 && lr < 10) red[w][u * 10 + lr] = g[r];
            }
        }
        __syncthreads();

        if (tid < 300) {
            const int s2 = tid / 100, r0 = tid % 100;
            gacc += red[s2 * 2][r0] + red[s2 * 2 + 1][r0];
        }
        // no barrier here: next red write is 2 barriers away (pack-B + P2-B)
    }
    if (tid < 300) atomicAdd(&attsum[(size_t)n * 300 + tid], gacc);
}

// ---------- mix: r13 structure, P4a via MFMA (NaN-fixed: predicated B-frag) ----------
// r15's NaN: B-frag elements at k>=10 read UNWRITTEN LDS (row tail) -> bf16 NaN
// bits, and 0 x NaN = NaN despite the zero-padded att rows. Fix: predicate the
// B-frag 4B words -- load only where k<10 (always inside the written region:
// max offset tl*10+9 <= 79), literal 0 elsewhere. Everything else = r15 (= r13
// + chunk-invariant att A-frags + 48 MFMAs/chunk replacing ~75% of P4a VALU).
__global__ __launch_bounds__(640) void k_mix(const float* __restrict__ x,
                                             const ushort_t* __restrict__ wbf,
                                             const float* __restrict__ bqkv,
                                             const float* __restrict__ attsum,
                                             const float* __restrict__ batt,
                                             const ushort_t* __restrict__ wfb,
                                             const float* __restrict__ bf,
                                             float* __restrict__ out,
                                             float* __restrict__ out_att0) {
    __shared__ ushort_t xT[80 * 104];    // 16,640 B; phase A: xT[p][c], phase B: y0T[p][sc] (YP)
    __shared__ ushort_t vls[96 * VP];    // 15,744 B  vls[o][p] bf16
    __shared__ float Als[304];           // -> 33,600 B total
    const int n = blockIdx.y, tcb = blockIdx.x;   // tcb in [0,16)
    const int tid = threadIdx.x;
    const int l = tid & 63, w = tid >> 6;         // w in [0,10)
    const int lr = l & 15, lh = l >> 4;
    const int ct = w >> 1, rth = w & 1;
    const int plocal = ct * 16 + lr;              // P2/FF column owned by this lane

    // fused attention finalize (once per block; tcb==0 writes att0 output)
    if (tid < 300) {
        const float a0 = tanh_inl(attsum[(size_t)n * 300 + tid] * (1.0f / 32768.0f));
        if (tcb == 0) out_att0[(size_t)n * 300 + tid] = a0;
        const int s = tid / 100, r = tid % 100, u = r / 10, v = r % 10;
        const int pu = (u / 2 + 4) % 5, pv = (v / 2 + 4) % 5;   // PART_BODY closed form
        Als[tid] = a0 + batt[((n * 3 + s) * 5 + pu) * 5 + pv];
    }

    // staging mapping (3 iters x 4 channels), identical to k_gram
    int c4a[3], ppa[3];
#pragma unroll
    for (int it = 0; it < 3; it++) {
        const int i = tid + it * 640;             // i < 1920
        c4a[it] = i / 80; ppa[it] = i % 80;
    }

    const float* xn = x + (size_t)n * CC * PP;
    float xr[12];
    {   // prologue: load chunk 0
        const float* xsrc = xn + (size_t)(tcb * MCH) * 80;
#pragma unroll
        for (int it = 0; it < 3; it++)
#pragma unroll
            for (int r = 0; r < 4; r++)
                xr[it * 4 + r] = xsrc[(size_t)(4 * c4a[it] + r) * PP + ppa[it]];
    }

    // ---- build chunk-invariant att A-frags: A_s[row=lr(u)][k=lh*8+e (v)] ----
    __syncthreads();   // Als visible to all
    s16x8 afrA[3];
#pragma unroll
    for (int s = 0; s < 3; s++) {
#pragma unroll
        for (int e = 0; e < 8; e++) {
            const int v = lh * 8 + e;
            const float val = (lr < 10 && v < 10) ? Als[s * 100 + lr * 10 + v] : 0.f;
            afrA[s][e] = (short)f2bf(val);
        }
    }

    for (int j = 0; j < MCH; j++) {
        const int tc80 = tcb * MCH + j;
        // ---- pack xr -> xT[p][c] (pitch 104, b64 writes) ----
#pragma unroll
        for (int it = 0; it < 3; it++) {
            const uint_t lo = (uint_t)f2bf(xr[it * 4 + 0]) | ((uint_t)f2bf(xr[it * 4 + 1]) << 16);
            const uint_t hi = (uint_t)f2bf(xr[it * 4 + 2]) | ((uint_t)f2bf(xr[it * 4 + 3]) << 16);
            *(ull_t*)&xT[ppa[it] * 104 + 4 * c4a[it]] = (ull_t)lo | ((ull_t)hi << 32);
        }
        __syncthreads();

        // ---- prefetch next chunk into regs; drains under P2/P4a/FF compute ----
        if (j + 1 < MCH) {
            const float* xsrc = xn + (size_t)(tc80 + 1) * 80;
#pragma unroll
            for (int it = 0; it < 3; it++)
#pragma unroll
                for (int r = 0; r < 4; r++)
                    xr[it * 4 + r] = xsrc[(size_t)(4 * c4a[it] + r) * PP + ppa[it]];
        }

        // ---- P2: v projection, 3 rt per wave, bf16 scatter to vls ----
        {
            s16x8 bfr[3];
#pragma unroll
            for (int kb = 0; kb < 3; kb++)
                bfr[kb] = *(const s16x8*)&xT[plocal * 104 + kb * 32 + lh * 8];
#pragma unroll
            for (int jj = 0; jj < 3; jj++) {
                const int rt = rth * 3 + jj;
                f32x4 acc = {0.f, 0.f, 0.f, 0.f};
#pragma unroll
                for (int kb = 0; kb < 3; kb++) {
                    const s16x8 afr = *(const s16x8*)&wbf[(size_t)(192 + rt * 16 + lr) * 96 + kb * 32 + lh * 8];
                    acc = __builtin_amdgcn_mfma_f32_16x16x32_bf16(afr, bfr[kb], acc, 0, 0, 0);
                }
                const int ob = 192 + rt * 16 + lh * 4;
                const float4 bb = *(const float4*)&bqkv[ob];
                const int o = rt * 16 + lh * 4;
                vls[(o + 0) * VP + plocal] = f2bf(acc[0] + bb.x);
                vls[(o + 1) * VP + plocal] = f2bf(acc[1] + bb.y);
                vls[(o + 2) * VP + plocal] = f2bf(acc[2] + bb.z);
                vls[(o + 3) * VP + plocal] = f2bf(acc[3] + bb.w);
            }
        }
        __syncthreads();

        // ---- P4a: y0 = att @ v via MFMA; 48 tasks (s,tl,half) over 10 waves ----
        for (int tk = w; tk < 48; tk += 10) {
            const int s = tk / 16, rem = tk - s * 16;
            const int tl = rem >> 1, half = rem & 1;
            const int scc = s * 32 + half * 16 + lr;     // vls row / y0T col
            union { uint_t u[4]; s16x8 v; } ub;          // B[col=lr][k=lh*8+e]
            const ushort_t* src = &vls[scc * VP + tl * 10 + lh * 8];
#pragma unroll
            for (int q = 0; q < 4; q++) {
                // load only where k = lh*8 + 2q (+1) < 10: lh=0 -> all 4 words,
                // lh=1 -> q=0 only (k=8,9). Never touches unwritten LDS; zero
                // words pair with the zero att columns (0 x 0 = 0, no NaN).
                ub.u[q] = (lh * 8 + 2 * q < 10) ? *(const uint_t*)(src + 2 * q) : 0u;
            }
            f32x4 acc = {0.f, 0.f, 0.f, 0.f};
            acc = __builtin_amdgcn_mfma_f32_16x16x32_bf16(afrA[s], ub.v, acc, 0, 0, 0);
#pragma unroll
            for (int r = 0; r < 4; r++) {
                const int u = lh * 4 + r;                // D row = u
                if (u < 10)
                    xT[(tl * 10 + u) * YP + scc] = f2bf(acc[r]);   // y0T write
            }
        }
        __syncthreads();

        // ---- FF: yfr from y0T (4x b32 per frag, 4B-aligned), 3 rt/wave, epilogue ----
        {
            s16x8 yfr[3];
#pragma unroll
            for (int kb = 0; kb < 3; kb++) {
                union { uint_t u[4]; s16x8 v; } yf;
#pragma unroll
                for (int q = 0; q < 4; q++)
                    yf.u[q] = *(const uint_t*)&xT[plocal * YP + kb * 32 + lh * 8 + q * 2];
                yfr[kb] = yf.v;
            }
            const size_t pbase = (size_t)n * CC * PP + (size_t)tc80 * 80;
#pragma unroll
            for (int jj = 0; jj < 3; jj++) {
                const int rt = rth * 3 + jj;
                const int ob = rt * 16 + lh * 4;
                float xr4[4];
#pragma unroll
                for (int r = 0; r < 4; r++)
                    xr4[r] = x[pbase + (size_t)(ob + r) * PP + plocal];
                f32x4 acc = {0.f, 0.f, 0.f, 0.f};
#pragma unroll
                for (int kb = 0; kb < 3; kb++) {
                    const s16x8 faf = *(const s16x8*)&wfb[(size_t)(rt * 16 + lr) * 96 + kb * 32 + lh * 8];
                    acc = __builtin_amdgcn_mfma_f32_16x16x32_bf16(faf, yfr[kb], acc, 0, 0, 0);
                }
                const float4 bb = *(const float4*)&bf[ob];
#pragma unroll
                for (int r = 0; r < 4; r++) {
                    const size_t idx = pbase + (size_t)(ob + r) * PP + plocal;
                    const float rr = xr4[r] + acc[r] + ((const float*)&bb)[r];
                    out[idx] = rr > 0.f ? rr : NEG * rr;
                }
            }
        }
        __syncthreads();   // protect xT (next pack) and vls (next P2 write)
    }
}

extern "C" void kernel_launch(void* const* d_in, const int* in_sizes, int n_in,
                              void* d_out, int out_size, void* d_ws, size_t ws_size,
                              hipStream_t stream) {
    const float* x    = (const float*)d_in[0];
    const float* batt = (const float*)d_in[1];
    const float* wqkv = (const float*)d_in[2];
    const float* bqkv = (const float*)d_in[3];
    const float* wff  = (const float*)d_in[4];
    const float* bff  = (const float*)d_in[5];
    const float* gam  = (const float*)d_in[6];
    const float* bet  = (const float*)d_in[7];
    const float* mu   = (const float*)d_in[8];
    const float* var  = (const float*)d_in[9];

    float* ws  = (float*)d_ws;
    float* out = (float*)d_out;
    float* out_att0 = out + (size_t)NN * CC * PP;

    float*    attsum = ws + OFF_ATT;
    ushort_t* wbf    = (ushort_t*)(ws + OFF_WBF);
    ushort_t* wfb    = (ushort_t*)(ws + OFF_WFB);
    float*    bfold  = ws + OFF_BF;

    hipLaunchKernelGGL(k_prep, dim3(64), dim3(256), 0, stream,
                       wqkv, wff, bff, gam, bet, mu, var, ws);
    hipLaunchKernelGGL(k_gram, dim3(128 / GCH, 32), dim3(640), 0, stream,
                       x, wbf, bqkv, attsum);
    hipLaunchKernelGGL(k_mix, dim3(128 / MCH, 32), dim3(640), 0, stream,
                       x, wbf, bqkv, attsum, batt, wfb, bfold, out, out_att0);
}

// Round 17
// 129.113 us; speedup vs baseline: 2.2410x; 2.2410x over previous
//
#include <hip/hip_runtime.h>
#include <cstddef>

#define NN 32
#define CC 96
#define TT 1024
#define PP 10240          // T*V, contiguous per (n,c)
#define NEG 0.1f
#define GCH 8             // k_gram: t-chunks per block (8 x 80p)
#define MCH 8             // k_mix:  80p-chunks per block (512 blocks = 2/CU, 1 cohort)

typedef __attribute__((ext_vector_type(8))) short s16x8;
typedef __attribute__((ext_vector_type(4))) float f32x4;
typedef unsigned short ushort_t;
typedef unsigned int uint_t;
typedef unsigned long long ull_t;

// ---- workspace layout (float offsets) ----
#define OFF_ATT  ((size_t)NN*128*300)              // attsum: f32 [N][300] (atomic accum)
#define OFF_WBF  (OFF_ATT + (size_t)NN*300)        // wbf: bf16 [288][96]
#define OFF_WFB  (OFF_WBF + (size_t)13824)         // wfb: bf16 [96][96] BN-folded
#define OFF_BF   (OFF_WFB + (size_t)4608)          // bfold: f32 [96]

#define VP 82      // vls pitch (ushorts) for 80-p tiles
#define YP 102     // y0T pitch: 51 words/row, gcd(51%32=19,32)=1 -> conflict-free writes

__device__ __forceinline__ ushort_t f2bf(float f) {
    union { float f; uint_t u; } a; a.f = f;
    const uint_t r = a.u + 0x7FFFu + ((a.u >> 16) & 1u);   // RNE
    return (ushort_t)(r >> 16);
}
__device__ __forceinline__ float bf2f(ushort_t h) {
    union { uint_t u; float f; } a; a.u = ((uint_t)h) << 16;
    return a.f;
}
// inline tanh: no OCML call, no branches. |err| ~1e-7.
__device__ __forceinline__ float tanh_inl(float z) {
    z = fminf(fmaxf(z, -10.f), 10.f);
    const float e2 = __expf(2.f * z);
    return (e2 - 1.f) / (e2 + 1.f);
}

// ---------- prep: bf16 weights + BN fold + attsum zero ----------
__global__ void k_prep(const float* __restrict__ wqkv, const float* __restrict__ wff,
                       const float* __restrict__ bff,  const float* __restrict__ gam,
                       const float* __restrict__ bet,  const float* __restrict__ mu,
                       const float* __restrict__ var,  float* __restrict__ ws) {
    const int i = blockIdx.x * 256 + threadIdx.x;
    const int stride = gridDim.x * 256;
    ushort_t* wbf = (ushort_t*)(ws + OFF_WBF);
    for (int j = i; j < 288 * 96; j += stride) wbf[j] = f2bf(wqkv[j]);   // row-major [o][c]
    ushort_t* wfb = (ushort_t*)(ws + OFF_WFB);
    for (int j = i; j < 96 * 96; j += stride) {
        const int o = j / 96;                    // row-major [o][sc]
        const float A = gam[o] * rsqrtf(var[o] + 1e-5f);
        wfb[j] = f2bf(wff[j] * A);
    }
    for (int j = i; j < 96; j += stride) {
        const float A = gam[j] * rsqrtf(var[j] + 1e-5f);
        ws[OFF_BF + j] = (bff[j] - mu[j]) * A + bet[j];
    }
    for (int j = i; j < NN * 300; j += stride) ws[OFF_ATT + j] = 0.f;   // atomic accum
}

// ---------- gram: pipelined chunk loop; q,k proj + gram partials -> 1 atomic ----------
// HW-verified ~34 us (r3-r13).
__global__ __launch_bounds__(640) void k_gram(const float* __restrict__ x,
                                              const ushort_t* __restrict__ wbf,
                                              const float* __restrict__ bqkv,
                                              float* __restrict__ attsum) {
    __shared__ ushort_t xT[80][104];        // 16,640 B  xT[p][c]
    __shared__ ushort_t qk[6][8][10][36];   // 34,560 B  [role*3+s][t][u][cp(pad36)]
    __shared__ float red[6][100];           //  2,400 B  -> 53,600 total
    const int n = blockIdx.y, tcb = blockIdx.x;    // tcb in [0,16)
    const int tid = threadIdx.x;
    const int l = tid & 63, w = tid >> 6;          // w in [0,10)
    const int lr = l & 15, lh = l >> 4;
    const int ct = w >> 1, rth = w & 1;
    const int p2p = ct * 16 + lr;                  // P2 column owned by this lane

    int c4a[3], ppa[3];
#pragma unroll
    for (int it = 0; it < 3; it++) {
        const int i = tid + it * 640;              // i < 1920
        c4a[it] = i / 80; ppa[it] = i % 80;
    }

    const float* xn = x + (size_t)n * CC * PP;
    float xr[12];
    {
        const float* xsrc = xn + (size_t)(tcb * GCH) * 80;
#pragma unroll
        for (int it = 0; it < 3; it++)
#pragma unroll
            for (int r = 0; r < 4; r++)
                xr[it * 4 + r] = xsrc[(size_t)(4 * c4a[it] + r) * PP + ppa[it]];
    }

    float gacc = 0.f;
    for (int j = 0; j < GCH; j++) {
        // ---- pack xr -> xT (bf16, 4-c packed b64 writes) ----
#pragma unroll
        for (int it = 0; it < 3; it++) {
            const uint_t lo = (uint_t)f2bf(xr[it * 4 + 0]) | ((uint_t)f2bf(xr[it * 4 + 1]) << 16);
            const uint_t hi = (uint_t)f2bf(xr[it * 4 + 2]) | ((uint_t)f2bf(xr[it * 4 + 3]) << 16);
            *(ull_t*)&xT[ppa[it]][4 * c4a[it]] = (ull_t)lo | ((ull_t)hi << 32);
        }
        __syncthreads();

        // ---- prefetch next chunk into regs; drains under P2+P3 compute ----
        if (j + 1 < GCH) {
            const float* xsrc = xn + (size_t)(tcb * GCH + j + 1) * 80;
#pragma unroll
            for (int it = 0; it < 3; it++)
#pragma unroll
                for (int r = 0; r < 4; r++)
                    xr[it * 4 + r] = xsrc[(size_t)(4 * c4a[it] + r) * PP + ppa[it]];
        }

        // ---- P2: q,k projection; 10 wave-tasks = 5 ct x 2 roles, 6 rt each ----
        {
            s16x8 bfr[3];
#pragma unroll
            for (int kb = 0; kb < 3; kb++)
                bfr[kb] = *(const s16x8*)&xT[p2p][kb * 32 + lh * 8];
            ushort_t* qkf = (ushort_t*)qk;
#pragma unroll
            for (int jj = 0; jj < 6; jj++) {
                const int rt = rth * 6 + jj;
                f32x4 acc = {0.f, 0.f, 0.f, 0.f};
#pragma unroll
                for (int kb = 0; kb < 3; kb++) {
                    const s16x8 afr = *(const s16x8*)&wbf[(size_t)(rt * 16 + lr) * 96 + kb * 32 + lh * 8];
                    acc = __builtin_amdgcn_mfma_f32_16x16x32_bf16(afr, bfr[kb], acc, 0, 0, 0);
                }
                const int obase = rt * 16 + lh * 4;
                const float4 bb = *(const float4*)&bqkv[obase];
                const int role = rth;                 // rt<6 -> q, rt>=6 -> k
                const int orem = obase - role * 96;
                const int s = orem >> 5, cp0 = orem & 31;
                const uint_t lo = (uint_t)f2bf(acc[0] + bb.x) | ((uint_t)f2bf(acc[1] + bb.y) << 16);
                const uint_t hi = (uint_t)f2bf(acc[2] + bb.z) | ((uint_t)f2bf(acc[3] + bb.w) << 16);
                *(ull_t*)(qkf + ((size_t)(role * 3 + s) * 80 + p2p) * 36 + cp0) =
                    (ull_t)lo | ((ull_t)hi << 32);    // 8B-aligned (72B rows)
            }
        }
        __syncthreads();

        // ---- P3: gram G_s[u][v] = sum_{cp,t} q[s,cp,t,u] k[s,cp,t,v] ----
        if (w < 6) {
            const int s = w >> 1, th = w & 1;
            const int uv = lr > 9 ? 9 : lr;     // clamp garbage rows/cols (discarded)
            f32x4 g = {0.f, 0.f, 0.f, 0.f};
#pragma unroll
            for (int t4 = 0; t4 < 4; t4++) {
                const int t = th * 4 + t4;
                const ushort_t* qp = &qk[s][t][uv][lh * 8];       // 8B-aligned
                const ushort_t* kp = &qk[3 + s][t][uv][lh * 8];
                union { ull_t u[2]; s16x8 v; } ua, ub;
                ua.u[0] = *(const ull_t*)qp;  ua.u[1] = *(const ull_t*)(qp + 4);
                ub.u[0] = *(const ull_t*)kp;  ub.u[1] = *(const ull_t*)(kp + 4);
                g = __builtin_amdgcn_mfma_f32_16x16x32_bf16(ua.v, ub.v, g, 0, 0, 0);
            }
#pragma unroll
            for (int r = 0; r < 4; r++) {
                const int u = lh * 4 + r;
                if (u < 10 && lr < 10) red[w][u * 10 + lr] = g[r];
            }
        }
        __syncthreads();

        if (tid < 300) {
            const int s2 = tid / 100, r0 = tid % 100;
            gacc += red[s2 * 2][r0] + red[s2 * 2 + 1][r0];
        }
        // no barrier here: next red write is 2 barriers away (pack-B + P2-B)
    }
    if (tid < 300) atomicAdd(&attsum[(size_t)n * 300 + tid], gacc);
}

// ---------- mix: r13 (session-best, 91 us): MCH=8 single cohort, bf16 vls,
// YP=102 conflict-reduced y0T, uniform 12-y0/thread scalar P4a ----------
__global__ __launch_bounds__(640) void k_mix(const float* __restrict__ x,
                                             const ushort_t* __restrict__ wbf,
                                             const float* __restrict__ bqkv,
                                             const float* __restrict__ attsum,
                                             const float* __restrict__ batt,
                                             const ushort_t* __restrict__ wfb,
                                             const float* __restrict__ bf,
                                             float* __restrict__ out,
                                             float* __restrict__ out_att0) {
    __shared__ ushort_t xT[80 * 104];    // 16,640 B; phase A: xT[p][c] (104), phase B: y0T[p][sc] (YP=102)
    __shared__ ushort_t vls[96 * VP];    // 15,744 B  vls[o][p]
    __shared__ float Als[304];           // -> 33,600 B total
    const int n = blockIdx.y, tcb = blockIdx.x;   // tcb in [0,16)
    const int tid = threadIdx.x;
    const int l = tid & 63, w = tid >> 6;         // w in [0,10)
    const int lr = l & 15, lh = l >> 4;
    const int ct = w >> 1, rth = w & 1;
    const int plocal = ct * 16 + lr;              // P2/FF column owned by this lane

    // fused attention finalize (once per block; tcb==0 writes att0 output)
    if (tid < 300) {
        const float a0 = tanh_inl(attsum[(size_t)n * 300 + tid] * (1.0f / 32768.0f));
        if (tcb == 0) out_att0[(size_t)n * 300 + tid] = a0;
        const int s = tid / 100, r = tid % 100, u = r / 10, v = r % 10;
        const int pu = (u / 2 + 4) % 5, pv = (v / 2 + 4) % 5;   // PART_BODY closed form
        Als[tid] = a0 + batt[((n * 3 + s) * 5 + pu) * 5 + pv];
    }

    // staging mapping (3 iters x 4 channels), identical to k_gram
    int c4a[3], ppa[3];
#pragma unroll
    for (int it = 0; it < 3; it++) {
        const int i = tid + it * 640;             // i < 1920
        c4a[it] = i / 80; ppa[it] = i % 80;
    }
    // P4a mapping (r8/r10): thread (g8 = tid/80, pcol = tid%80) computes 12 y0
    const int g8 = tid / 80;                      // group 0..7
    const int pcol = tid - g8 * 80;               // 0..79
    const int ucol = pcol % 10;
    const int tlb = pcol - ucol;                  // tl*10

    const float* xn = x + (size_t)n * CC * PP;
    float xr[12];
    {   // prologue: load chunk 0
        const float* xsrc = xn + (size_t)(tcb * MCH) * 80;
#pragma unroll
        for (int it = 0; it < 3; it++)
#pragma unroll
            for (int r = 0; r < 4; r++)
                xr[it * 4 + r] = xsrc[(size_t)(4 * c4a[it] + r) * PP + ppa[it]];
    }

    for (int j = 0; j < MCH; j++) {
        const int tc80 = tcb * MCH + j;
        // ---- pack xr -> xT[p][c] (pitch 104, b64 writes) ----
#pragma unroll
        for (int it = 0; it < 3; it++) {
            const uint_t lo = (uint_t)f2bf(xr[it * 4 + 0]) | ((uint_t)f2bf(xr[it * 4 + 1]) << 16);
            const uint_t hi = (uint_t)f2bf(xr[it * 4 + 2]) | ((uint_t)f2bf(xr[it * 4 + 3]) << 16);
            *(ull_t*)&xT[ppa[it] * 104 + 4 * c4a[it]] = (ull_t)lo | ((ull_t)hi << 32);
        }
        __syncthreads();

        // ---- prefetch next chunk into regs; drains under P2/P4a/FF compute ----
        if (j + 1 < MCH) {
            const float* xsrc = xn + (size_t)(tc80 + 1) * 80;
#pragma unroll
            for (int it = 0; it < 3; it++)
#pragma unroll
                for (int r = 0; r < 4; r++)
                    xr[it * 4 + r] = xsrc[(size_t)(4 * c4a[it] + r) * PP + ppa[it]];
        }

        // ---- P2: v projection, 3 rt per wave, immediate scatter to vls ----
        {
            s16x8 bfr[3];
#pragma unroll
            for (int kb = 0; kb < 3; kb++)
                bfr[kb] = *(const s16x8*)&xT[plocal * 104 + kb * 32 + lh * 8];
#pragma unroll
            for (int jj = 0; jj < 3; jj++) {
                const int rt = rth * 3 + jj;
                f32x4 acc = {0.f, 0.f, 0.f, 0.f};
#pragma unroll
                for (int kb = 0; kb < 3; kb++) {
                    const s16x8 afr = *(const s16x8*)&wbf[(size_t)(192 + rt * 16 + lr) * 96 + kb * 32 + lh * 8];
                    acc = __builtin_amdgcn_mfma_f32_16x16x32_bf16(afr, bfr[kb], acc, 0, 0, 0);
                }
                const int ob = 192 + rt * 16 + lh * 4;
                const float4 bb = *(const float4*)&bqkv[ob];
                const int o = rt * 16 + lh * 4;
                vls[(o + 0) * VP + plocal] = f2bf(acc[0] + bb.x);
                vls[(o + 1) * VP + plocal] = f2bf(acc[1] + bb.y);
                vls[(o + 2) * VP + plocal] = f2bf(acc[2] + bb.z);
                vls[(o + 3) * VP + plocal] = f2bf(acc[3] + bb.w);
            }
        }
        __syncthreads();

        // ---- P4a: y0 = att @ v; 12 values per thread -> y0T[p][sc] (pitch YP) ----
        {
            float aqk[10];
#pragma unroll
            for (int m = 0; m < 12; m++) {
                if ((m & 3) == 0) {                  // s = m>>2 is a literal per unroll
                    const int s = m >> 2;
#pragma unroll
                    for (int v = 0; v < 10; v++) aqk[v] = Als[s * 100 + ucol * 10 + v];
                }
                const int sc = m * 8 + g8;
                const ushort_t* vr = &vls[sc * VP + tlb];
                float y0 = 0.f;
#pragma unroll
                for (int h = 0; h < 5; h++) {
                    const uint_t two = *(const uint_t*)(vr + 2 * h);  // 4B-aligned
                    union { uint_t uu; float ff; } lo, hi;
                    lo.uu = two << 16;
                    hi.uu = two & 0xFFFF0000u;
                    y0 = fmaf(aqk[2 * h],     lo.ff, y0);
                    y0 = fmaf(aqk[2 * h + 1], hi.ff, y0);
                }
                xT[pcol * YP + sc] = f2bf(y0);       // y0T write, conflict-free banks
            }
        }
        __syncthreads();

        // ---- FF: yfr from y0T (4x b32 per frag, 4B-aligned), 3 rt/wave, epilogue ----
        {
            s16x8 yfr[3];
#pragma unroll
            for (int kb = 0; kb < 3; kb++) {
                union { uint_t u[4]; s16x8 v; } yf;
#pragma unroll
                for (int q = 0; q < 4; q++)
                    yf.u[q] = *(const uint_t*)&xT[plocal * YP + kb * 32 + lh * 8 + q * 2];
                yfr[kb] = yf.v;
            }
            const size_t pbase = (size_t)n * CC * PP + (size_t)tc80 * 80;
#pragma unroll
            for (int jj = 0; jj < 3; jj++) {
                const int rt = rth * 3 + jj;
                const int ob = rt * 16 + lh * 4;
                float xr4[4];
#pragma unroll
                for (int r = 0; r < 4; r++)
                    xr4[r] = x[pbase + (size_t)(ob + r) * PP + plocal];
                f32x4 acc = {0.f, 0.f, 0.f, 0.f};
#pragma unroll
                for (int kb = 0; kb < 3; kb++) {
                    const s16x8 faf = *(const s16x8*)&wfb[(size_t)(rt * 16 + lr) * 96 + kb * 32 + lh * 8];
                    acc = __builtin_amdgcn_mfma_f32_16x16x32_bf16(faf, yfr[kb], acc, 0, 0, 0);
                }
                const float4 bb = *(const float4*)&bf[ob];
#pragma unroll
                for (int r = 0; r < 4; r++) {
                    const size_t idx = pbase + (size_t)(ob + r) * PP + plocal;
                    const float rr = xr4[r] + acc[r] + ((const float*)&bb)[r];
                    out[idx] = rr > 0.f ? rr : NEG * rr;
                }
            }
        }
        __syncthreads();   // protect xT (next pack) and vls (next P2 write)
    }
}

extern "C" void kernel_launch(void* const* d_in, const int* in_sizes, int n_in,
                              void* d_out, int out_size, void* d_ws, size_t ws_size,
                              hipStream_t stream) {
    const float* x    = (const float*)d_in[0];
    const float* batt = (const float*)d_in[1];
    const float* wqkv = (const float*)d_in[2];
    const float* bqkv = (const float*)d_in[3];
    const float* wff  = (const float*)d_in[4];
    const float* bff  = (const float*)d_in[5];
    const float* gam  = (const float*)d_in[6];
    const float* bet  = (const float*)d_in[7];
    const float* mu   = (const float*)d_in[8];
    const float* var  = (const float*)d_in[9];

    float* ws  = (float*)d_ws;
    float* out = (float*)d_out;
    float* out_att0 = out + (size_t)NN * CC * PP;

    float*    attsum = ws + OFF_ATT;
    ushort_t* wbf    = (ushort_t*)(ws + OFF_WBF);
    ushort_t* wfb    = (ushort_t*)(ws + OFF_WFB);
    float*    bfold  = ws + OFF_BF;

    hipLaunchKernelGGL(k_prep, dim3(64), dim3(256), 0, stream,
                       wqkv, wff, bff, gam, bet, mu, var, ws);
    hipLaunchKernelGGL(k_gram, dim3(128 / GCH, 32), dim3(640), 0, stream,
                       x, wbf, bqkv, attsum);
    hipLaunchKernelGGL(k_mix, dim3(128 / MCH, 32), dim3(640), 0, stream,
                       x, wbf, bqkv, attsum, batt, wfb, bfold, out, out_att0);
}

// Round 19
// 128.783 us; speedup vs baseline: 2.2467x; 1.0026x over previous
//
#include <hip/hip_runtime.h>
#include <cstddef>

#define NN 32
#define CC 96
#define TT 1024
#define PP 10240          // T*V, contiguous per (n,c)
#define NEG 0.1f
#define GCH 8             // k_gram: t-chunks per block (8 x 80p)
#define MCH 8             // k_mix:  80p-chunks per block (512 blocks = 2/CU, 1 cohort)

typedef __attribute__((ext_vector_type(8))) short s16x8;
typedef __attribute__((ext_vector_type(4))) float f32x4;
typedef unsigned short ushort_t;
typedef unsigned int uint_t;
typedef unsigned long long ull_t;

// ---- workspace layout (float offsets) ----
#define OFF_ATT  ((size_t)NN*128*300)              // attsum: f32 [N][300] (atomic accum)
#define OFF_WBF  (OFF_ATT + (size_t)NN*300)        // wbf: bf16 [288][96]
#define OFF_WFB  (OFF_WBF + (size_t)13824)         // wfb: bf16 [96][96] BN-folded
#define OFF_BF   (OFF_WFB + (size_t)4608)          // bfold: f32 [96]

#define VP 82      // vls pitch (ushorts) for 80-p tiles
#define YP 102     // y0T pitch: 51 words/row, gcd(51%32=19,32)=1 -> conflict-free writes

__device__ __forceinline__ ushort_t f2bf(float f) {
    union { float f; uint_t u; } a; a.f = f;
    const uint_t r = a.u + 0x7FFFu + ((a.u >> 16) & 1u);   // RNE
    return (ushort_t)(r >> 16);
}
__device__ __forceinline__ float bf2f(ushort_t h) {
    union { uint_t u; float f; } a; a.u = ((uint_t)h) << 16;
    return a.f;
}
// inline tanh: no OCML call, no branches. |err| ~1e-7.
__device__ __forceinline__ float tanh_inl(float z) {
    z = fminf(fmaxf(z, -10.f), 10.f);
    const float e2 = __expf(2.f * z);
    return (e2 - 1.f) / (e2 + 1.f);
}

// ---------- prep: bf16 weights + BN fold + attsum zero ----------
__global__ void k_prep(const float* __restrict__ wqkv, const float* __restrict__ wff,
                       const float* __restrict__ bff,  const float* __restrict__ gam,
                       const float* __restrict__ bet,  const float* __restrict__ mu,
                       const float* __restrict__ var,  float* __restrict__ ws) {
    const int i = blockIdx.x * 256 + threadIdx.x;
    const int stride = gridDim.x * 256;
    ushort_t* wbf = (ushort_t*)(ws + OFF_WBF);
    for (int j = i; j < 288 * 96; j += stride) wbf[j] = f2bf(wqkv[j]);   // row-major [o][c]
    ushort_t* wfb = (ushort_t*)(ws + OFF_WFB);
    for (int j = i; j < 96 * 96; j += stride) {
        const int o = j / 96;                    // row-major [o][sc]
        const float A = gam[o] * rsqrtf(var[o] + 1e-5f);
        wfb[j] = f2bf(wff[j] * A);
    }
    for (int j = i; j < 96; j += stride) {
        const float A = gam[j] * rsqrtf(var[j] + 1e-5f);
        ws[OFF_BF + j] = (bff[j] - mu[j]) * A + bet[j];
    }
    for (int j = i; j < NN * 300; j += stride) ws[OFF_ATT + j] = 0.f;   // atomic accum
}

// ---------- gram: pipelined chunk loop; q,k proj + gram partials -> 1 atomic ----------
// HW-verified ~34 us (r3-r17). VGPR 48.
__global__ __launch_bounds__(640) void k_gram(const float* __restrict__ x,
                                              const ushort_t* __restrict__ wbf,
                                              const float* __restrict__ bqkv,
                                              float* __restrict__ attsum) {
    __shared__ ushort_t xT[80][104];        // 16,640 B  xT[p][c]
    __shared__ ushort_t qk[6][8][10][36];   // 34,560 B  [role*3+s][t][u][cp(pad36)]
    __shared__ float red[6][100];           //  2,400 B  -> 53,600 total
    const int n = blockIdx.y, tcb = blockIdx.x;    // tcb in [0,16)
    const int tid = threadIdx.x;
    const int l = tid & 63, w = tid >> 6;          // w in [0,10)
    const int lr = l & 15, lh = l >> 4;
    const int ct = w >> 1, rth = w & 1;
    const int p2p = ct * 16 + lr;                  // P2 column owned by this lane

    int c4a[3], ppa[3];
#pragma unroll
    for (int it = 0; it < 3; it++) {
        const int i = tid + it * 640;              // i < 1920
        c4a[it] = i / 80; ppa[it] = i % 80;
    }

    const float* xn = x + (size_t)n * CC * PP;
    float xr[12];
    {
        const float* xsrc = xn + (size_t)(tcb * GCH) * 80;
#pragma unroll
        for (int it = 0; it < 3; it++)
#pragma unroll
            for (int r = 0; r < 4; r++)
                xr[it * 4 + r] = xsrc[(size_t)(4 * c4a[it] + r) * PP + ppa[it]];
    }

    float gacc = 0.f;
    for (int j = 0; j < GCH; j++) {
        // ---- pack xr -> xT (bf16, 4-c packed b64 writes) ----
#pragma unroll
        for (int it = 0; it < 3; it++) {
            const uint_t lo = (uint_t)f2bf(xr[it * 4 + 0]) | ((uint_t)f2bf(xr[it * 4 + 1]) << 16);
            const uint_t hi = (uint_t)f2bf(xr[it * 4 + 2]) | ((uint_t)f2bf(xr[it * 4 + 3]) << 16);
            *(ull_t*)&xT[ppa[it]][4 * c4a[it]] = (ull_t)lo | ((ull_t)hi << 32);
        }
        __syncthreads();

        // ---- prefetch next chunk into regs; drains under P2+P3 compute ----
        if (j + 1 < GCH) {
            const float* xsrc = xn + (size_t)(tcb * GCH + j + 1) * 80;
#pragma unroll
            for (int it = 0; it < 3; it++)
#pragma unroll
                for (int r = 0; r < 4; r++)
                    xr[it * 4 + r] = xsrc[(size_t)(4 * c4a[it] + r) * PP + ppa[it]];
        }

        // ---- P2: q,k projection; 10 wave-tasks = 5 ct x 2 roles, 6 rt each ----
        {
            s16x8 bfr[3];
#pragma unroll
            for (int kb = 0; kb < 3; kb++)
                bfr[kb] = *(const s16x8*)&xT[p2p][kb * 32 + lh * 8];
            ushort_t* qkf = (ushort_t*)qk;
#pragma unroll
            for (int jj = 0; jj < 6; jj++) {
                const int rt = rth * 6 + jj;
                f32x4 acc = {0.f, 0.f, 0.f, 0.f};
#pragma unroll
                for (int kb = 0; kb < 3; kb++) {
                    const s16x8 afr = *(const s16x8*)&wbf[(size_t)(rt * 16 + lr) * 96 + kb * 32 + lh * 8];
                    acc = __builtin_amdgcn_mfma_f32_16x16x32_bf16(afr, bfr[kb], acc, 0, 0, 0);
                }
                const int obase = rt * 16 + lh * 4;
                const float4 bb = *(const float4*)&bqkv[obase];
                const int role = rth;                 // rt<6 -> q, rt>=6 -> k
                const int orem = obase - role * 96;
                const int s = orem >> 5, cp0 = orem & 31;
                const uint_t lo = (uint_t)f2bf(acc[0] + bb.x) | ((uint_t)f2bf(acc[1] + bb.y) << 16);
                const uint_t hi = (uint_t)f2bf(acc[2] + bb.z) | ((uint_t)f2bf(acc[3] + bb.w) << 16);
                *(ull_t*)(qkf + ((size_t)(role * 3 + s) * 80 + p2p) * 36 + cp0) =
                    (ull_t)lo | ((ull_t)hi << 32);    // 8B-aligned (72B rows)
            }
        }
        __syncthreads();

        // ---- P3: gram G_s[u][v] = sum_{cp,t} q[s,cp,t,u] k[s,cp,t,v] ----
        if (w < 6) {
            const int s = w >> 1, th = w & 1;
            const int uv = lr > 9 ? 9 : lr;     // clamp garbage rows/cols (discarded)
            f32x4 g = {0.f, 0.f, 0.f, 0.f};
#pragma unroll
            for (int t4 = 0; t4 < 4; t4++) {
                const int t = th * 4 + t4;
                const ushort_t* qp = &qk[s][t][uv][lh * 8];       // 8B-aligned
                const ushort_t* kp = &qk[3 + s][t][uv][lh * 8];
                union { ull_t u[2]; s16x8 v; } ua, ub;
                ua.u[0] = *(const ull_t*)qp;  ua.u[1] = *(const ull_t*)(qp + 4);
                ub.u[0] = *(const ull_t*)kp;  ub.u[1] = *(const ull_t*)(kp + 4);
                g = __builtin_amdgcn_mfma_f32_16x16x32_bf16(ua.v, ub.v, g, 0, 0, 0);
            }
#pragma unroll
            for (int r = 0; r < 4; r++) {
                const int u = lh * 4 + r;
                if (u < 10 && lr < 10) red[w][u * 10 + lr] = g[r];
            }
        }
        __syncthreads();

        if (tid < 300) {
            const int s2 = tid / 100, r0 = tid % 100;
            gacc += red[s2 * 2][r0] + red[s2 * 2 + 1][r0];
        }
        // no barrier here: next red write is 2 barriers away (pack-B + P2-B)
    }
    if (tid < 300) atomicAdd(&attsum[(size_t)n * 300 + tid], gacc);
}

// ---------- mix: session-best r13 (91 us, VGPR 84, verified twice at 129 total):
// MCH=8 single cohort, bf16 vls, YP=102 conflict-reduced y0T, 12-y0/thread P4a ----------
__global__ __launch_bounds__(640) void k_mix(const float* __restrict__ x,
                                             const ushort_t* __restrict__ wbf,
                                             const float* __restrict__ bqkv,
                                             const float* __restrict__ attsum,
                                             const float* __restrict__ batt,
                                             const ushort_t* __restrict__ wfb,
                                             const float* __restrict__ bf,
                                             float* __restrict__ out,
                                             float* __restrict__ out_att0) {
    __shared__ ushort_t xT[80 * 104];    // 16,640 B; phase A: xT[p][c] (104), phase B: y0T[p][sc] (YP=102)
    __shared__ ushort_t vls[96 * VP];    // 15,744 B  vls[o][p]
    __shared__ float Als[304];           // -> 33,600 B total
    const int n = blockIdx.y, tcb = blockIdx.x;   // tcb in [0,16)
    const int tid = threadIdx.x;
    const int l = tid & 63, w = tid >> 6;         // w in [0,10)
    const int lr = l & 15, lh = l >> 4;
    const int ct = w >> 1, rth = w & 1;
    const int plocal = ct * 16 + lr;              // P2/FF column owned by this lane

    // fused attention finalize (once per block; tcb==0 writes att0 output)
    if (tid < 300) {
        const float a0 = tanh_inl(attsum[(size_t)n * 300 + tid] * (1.0f / 32768.0f));
        if (tcb == 0) out_att0[(size_t)n * 300 + tid] = a0;
        const int s = tid / 100, r = tid % 100, u = r / 10, v = r % 10;
        const int pu = (u / 2 + 4) % 5, pv = (v / 2 + 4) % 5;   // PART_BODY closed form
        Als[tid] = a0 + batt[((n * 3 + s) * 5 + pu) * 5 + pv];
    }

    // staging mapping (3 iters x 4 channels), identical to k_gram
    int c4a[3], ppa[3];
#pragma unroll
    for (int it = 0; it < 3; it++) {
        const int i = tid + it * 640;             // i < 1920
        c4a[it] = i / 80; ppa[it] = i % 80;
    }
    // P4a mapping: thread (g8 = tid/80, pcol = tid%80) computes 12 y0
    const int g8 = tid / 80;                      // group 0..7
    const int pcol = tid - g8 * 80;               // 0..79
    const int ucol = pcol % 10;
    const int tlb = pcol - ucol;                  // tl*10

    const float* xn = x + (size_t)n * CC * PP;
    float xr[12];
    {   // prologue: load chunk 0
        const float* xsrc = xn + (size_t)(tcb * MCH) * 80;
#pragma unroll
        for (int it = 0; it < 3; it++)
#pragma unroll
            for (int r = 0; r < 4; r++)
                xr[it * 4 + r] = xsrc[(size_t)(4 * c4a[it] + r) * PP + ppa[it]];
    }

    for (int j = 0; j < MCH; j++) {
        const int tc80 = tcb * MCH + j;
        // ---- pack xr -> xT[p][c] (pitch 104, b64 writes) ----
#pragma unroll
        for (int it = 0; it < 3; it++) {
            const uint_t lo = (uint_t)f2bf(xr[it * 4 + 0]) | ((uint_t)f2bf(xr[it * 4 + 1]) << 16);
            const uint_t hi = (uint_t)f2bf(xr[it * 4 + 2]) | ((uint_t)f2bf(xr[it * 4 + 3]) << 16);
            *(ull_t*)&xT[ppa[it] * 104 + 4 * c4a[it]] = (ull_t)lo | ((ull_t)hi << 32);
        }
        __syncthreads();

        // ---- prefetch next chunk into regs; drains under P2/P4a/FF compute ----
        if (j + 1 < MCH) {
            const float* xsrc = xn + (size_t)(tc80 + 1) * 80;
#pragma unroll
            for (int it = 0; it < 3; it++)
#pragma unroll
                for (int r = 0; r < 4; r++)
                    xr[it * 4 + r] = xsrc[(size_t)(4 * c4a[it] + r) * PP + ppa[it]];
        }

        // ---- P2: v projection, 3 rt per wave, immediate scatter to vls ----
        {
            s16x8 bfr[3];
#pragma unroll
            for (int kb = 0; kb < 3; kb++)
                bfr[kb] = *(const s16x8*)&xT[plocal * 104 + kb * 32 + lh * 8];
#pragma unroll
            for (int jj = 0; jj < 3; jj++) {
                const int rt = rth * 3 + jj;
                f32x4 acc = {0.f, 0.f, 0.f, 0.f};
#pragma unroll
                for (int kb = 0; kb < 3; kb++) {
                    const s16x8 afr = *(const s16x8*)&wbf[(size_t)(192 + rt * 16 + lr) * 96 + kb * 32 + lh * 8];
                    acc = __builtin_amdgcn_mfma_f32_16x16x32_bf16(afr, bfr[kb], acc, 0, 0, 0);
                }
                const int ob = 192 + rt * 16 + lh * 4;
                const float4 bb = *(const float4*)&bqkv[ob];
                const int o = rt * 16 + lh * 4;
                vls[(o + 0) * VP + plocal] = f2bf(acc[0] + bb.x);
                vls[(o + 1) * VP + plocal] = f2bf(acc[1] + bb.y);
                vls[(o + 2) * VP + plocal] = f2bf(acc[2] + bb.z);
                vls[(o + 3) * VP + plocal] = f2bf(acc[3] + bb.w);
            }
        }
        __syncthreads();

        // ---- P4a: y0 = att @ v; 12 values per thread -> y0T[p][sc] (pitch YP) ----
        {
            float aqk[10];
#pragma unroll
            for (int m = 0; m < 12; m++) {
                if ((m & 3) == 0) {                  // s = m>>2 is a literal per unroll
                    const int s = m >> 2;
#pragma unroll
                    for (int v = 0; v < 10; v++) aqk[v] = Als[s * 100 + ucol * 10 + v];
                }
                const int sc = m * 8 + g8;
                const ushort_t* vr = &vls[sc * VP + tlb];
                float y0 = 0.f;
#pragma unroll
                for (int h = 0; h < 5; h++) {
                    const uint_t two = *(const uint_t*)(vr + 2 * h);  // 4B-aligned
                    union { uint_t uu; float ff; } lo, hi;
                    lo.uu = two << 16;
                    hi.uu = two & 0xFFFF0000u;
                    y0 = fmaf(aqk[2 * h],     lo.ff, y0);
                    y0 = fmaf(aqk[2 * h + 1], hi.ff, y0);
                }
                xT[pcol * YP + sc] = f2bf(y0);       // y0T write, conflict-free banks
            }
        }
        __syncthreads();

        // ---- FF: yfr from y0T (4x b32 per frag, 4B-aligned), 3 rt/wave, epilogue ----
        {
            s16x8 yfr[3];
#pragma unroll
            for (int kb = 0; kb < 3; kb++) {
                union { uint_t u[4]; s16x8 v; } yf;
#pragma unroll
                for (int q = 0; q < 4; q++)
                    yf.u[q] = *(const uint_t*)&xT[plocal * YP + kb * 32 + lh * 8 + q * 2];
                yfr[kb] = yf.v;
            }
            const size_t pbase = (size_t)n * CC * PP + (size_t)tc80 * 80;
#pragma unroll
            for (int jj = 0; jj < 3; jj++) {
                const int rt = rth * 3 + jj;
                const int ob = rt * 16 + lh * 4;
                float xr4[4];
#pragma unroll
                for (int r = 0; r < 4; r++)
                    xr4[r] = x[pbase + (size_t)(ob + r) * PP + plocal];
                f32x4 acc = {0.f, 0.f, 0.f, 0.f};
#pragma unroll
                for (int kb = 0; kb < 3; kb++) {
                    const s16x8 faf = *(const s16x8*)&wfb[(size_t)(rt * 16 + lr) * 96 + kb * 32 + lh * 8];
                    acc = __builtin_amdgcn_mfma_f32_16x16x32_bf16(faf, yfr[kb], acc, 0, 0, 0);
                }
                const float4 bb = *(const float4*)&bf[ob];
#pragma unroll
                for (int r = 0; r < 4; r++) {
                    const size_t idx = pbase + (size_t)(ob + r) * PP + plocal;
                    const float rr = xr4[r] + acc[r] + ((const float*)&bb)[r];
                    out[idx] = rr > 0.f ? rr : NEG * rr;
                }
            }
        }
        __syncthreads();   // protect xT (next pack) and vls (next P2 write)
    }
}

extern "C" void kernel_launch(void* const* d_in, const int* in_sizes, int n_in,
                              void* d_out, int out_size, void* d_ws, size_t ws_size,
                              hipStream_t stream) {
    const float* x    = (const float*)d_in[0];
    const float* batt = (const float*)d_in[1];
    const float* wqkv = (const float*)d_in[2];
    const float* bqkv = (const float*)d_in[3];
    const float* wff  = (const float*)d_in[4];
    const float* bff  = (const float*)d_in[5];
    const float* gam  = (const float*)d_in[6];
    const float* bet  = (const float*)d_in[7];
    const float* mu   = (const float*)d_in[8];
    const float* var  = (const float*)d_in[9];

    float* ws  = (float*)d_ws;
    float* out = (float*)d_out;
    float* out_att0 = out + (size_t)NN * CC * PP;

    float*    attsum = ws + OFF_ATT;
    ushort_t* wbf    = (ushort_t*)(ws + OFF_WBF);
    ushort_t* wfb    = (ushort_t*)(ws + OFF_WFB);
    float*    bfold  = ws + OFF_BF;

    hipLaunchKernelGGL(k_prep, dim3(64), dim3(256), 0, stream,
                       wqkv, wff, bff, gam, bet, mu, var, ws);
    hipLaunchKernelGGL(k_gram, dim3(128 / GCH, 32), dim3(640), 0, stream,
                       x, wbf, bqkv, attsum);
    hipLaunchKernelGGL(k_mix, dim3(128 / MCH, 32), dim3(640), 0, stream,
                       x, wbf, bqkv, attsum, batt, wfb, bfold, out, out_att0);
}